// Round 1
// baseline (1610.584 us; speedup 1.0000x reference)
//
#include <hip/hip_runtime.h>
#include <hip/hip_bf16.h>
#include <stdint.h>

#define HWDIM 48
#define PLANE 2304            // 48*48
#define NB 8
#define NT 12
#define CHID 96
#define CIN 192               // C + HID
#define OC 384                // 4*HID
#define KTOT 1728             // CIN*9
#define BN 64                 // spatial cols per block
#define NBLK_JOB 288          // 18432 / 64
#define ASTR 40               // padded LDS stride (bf16 elems) = 80B (16B-aligned, 2-way banks)
#define NCHUNK 54             // 1728 / 32

typedef __attribute__((ext_vector_type(8))) short short8;
typedef __attribute__((ext_vector_type(4))) float f32x4;

__device__ __forceinline__ unsigned short f2bf(float f) {
  union { float f; uint32_t u; } x; x.f = f;
  uint32_t u = x.u;
  return (unsigned short)((u + 0x7FFFu + ((u >> 16) & 1u)) >> 16);  // RNE
}

struct Job {
  const float* x_base; long long x_bs;   // x input: base + b*x_bs + ic*PLANE + y*48+x
  const float* h_base; long long h_bs;   // h_prev input
  const unsigned short* w;               // bf16 weights [384][1728], k=(kh*3+kw)*192+ic
  const float* bias;                     // [384]
  float* c_base;                         // c state, b-stride 96*PLANE
  float* h_out; long long ho_bs;         // h output (all_hidden slot)
  float* hf;                             // final-h slot or nullptr, b-stride 96*PLANE
};

// Weight repack: W[l][oc][ic][kh][kw] f32 -> Wb[(l*384+oc)*1728 + (kh*3+kw)*192+ic] bf16
__global__ void convlstm_wconv(const float* __restrict__ W, unsigned short* __restrict__ Wb, int total) {
  int idx = blockIdx.x * 256 + threadIdx.x;
  if (idx >= total) return;
  int k = idx % KTOT;
  int rest = idx / KTOT;          // l*384 + oc
  int ic = k % CIN;
  int w = k / CIN;                // kh*3 + kw
  float v = W[((size_t)rest * CIN + ic) * 9 + w];
  Wb[idx] = f2bf(v);
}

__global__ __launch_bounds__(256, 2) void convlstm_step(Job j0, Job j1) {
  __shared__ __align__(16) unsigned short A_lds[OC * ASTR];   // weights chunk [384][32] padded
  __shared__ __align__(16) unsigned short B_lds[BN * ASTR];   // im2col chunk, transposed [n][32] padded

  const int tid = threadIdx.x;
  const Job j = (blockIdx.x < NBLK_JOB) ? j0 : j1;
  const int n0 = (blockIdx.x % NBLK_JOB) * BN;

  const int lane = tid & 63;
  const int wv = tid >> 6;              // wave id 0..3, owns cols [16*wv, 16*wv+16)
  const int rbase = (lane >> 4) * 4;    // D-row base within 16-row fragment

  // ---- accumulators, init with bias (gate ch = m*16 + rbase + r) ----
  f32x4 acc[24];
#pragma unroll
  for (int m = 0; m < 24; ++m)
    acc[m] = *(const f32x4*)(j.bias + m * 16 + rbase);

  // ---- staging thread roles ----
  // A: thread loads rows (tid>>2) + 64*rr, k-quarter (tid&3)*8
  const int arow0 = tid >> 2;
  const int akq = tid & 3;
  // B: thread owns spatial col n=(tid&63), k-group (tid>>6)*8
  const int bn = tid & 63;
  const int bkg = tid >> 6;
  const int s = n0 + bn;
  const int bb = s / PLANE;             // batch (2304 % 64 == 0 -> uniform per block)
  const int sp = s % PLANE;
  const int y = sp / HWDIM;
  const int x = sp % HWDIM;

  for (int c = 0; c < NCHUNK; ++c) {
    const int k0 = c * 32;
    const int wdx = c / 6;              // conv tap 0..8 (uniform over chunk)
    const int icc = c - wdx * 6;        // in-ch chunk 0..5 (0-2: x source, 3-5: h source)
    const int kh = wdx / 3, kw = wdx - kh * 3;

    // load A chunk to regs (global bf16, 16B coalesced-ish, L2-hot)
    short8 av[6];
#pragma unroll
    for (int rr = 0; rr < 6; ++rr) {
      const int row = arow0 + rr * 64;
      av[rr] = *(const short8*)(j.w + (size_t)row * KTOT + k0 + akq * 8);
    }
    // load B chunk to regs (im2col with zero pad, f32 -> bf16)
    const int yy = y + kh - 1, xx = x + kw - 1;
    const bool valid = ((unsigned)yy < HWDIM) && ((unsigned)xx < HWDIM);
    const int ic0 = icc * 32 + bkg * 8;
    const float* src;
    if (icc < 3) src = j.x_base + (size_t)bb * j.x_bs + (size_t)ic0 * PLANE;
    else         src = j.h_base + (size_t)bb * j.h_bs + (size_t)(ic0 - 96) * PLANE;
    src += yy * HWDIM + xx;
    float bv[8];
#pragma unroll
    for (int i = 0; i < 8; ++i) bv[i] = valid ? src[(size_t)i * PLANE] : 0.f;

    __syncthreads();   // previous chunk's compute done reading LDS
#pragma unroll
    for (int rr = 0; rr < 6; ++rr)
      *(short8*)&A_lds[(arow0 + rr * 64) * ASTR + akq * 8] = av[rr];
    {
      short8 pb;
#pragma unroll
      for (int i = 0; i < 8; ++i) pb[i] = (short)f2bf(bv[i]);
      *(short8*)&B_lds[bn * ASTR + bkg * 8] = pb;
    }
    __syncthreads();

    // ---- MFMA: D[384 x 16] per wave, K=32 ----
    const short8 bf = *(const short8*)&B_lds[(wv * 16 + (lane & 15)) * ASTR + (lane >> 4) * 8];
#pragma unroll
    for (int m = 0; m < 24; ++m) {
      const short8 af = *(const short8*)&A_lds[(m * 16 + (lane & 15)) * ASTR + (lane >> 4) * 8];
      acc[m] = __builtin_amdgcn_mfma_f32_16x16x32_bf16(af, bf, acc[m], 0, 0, 0);
    }
  }

  // ---- fused LSTM epilogue: lane holds i/f/o/g for ch = m*16+rbase+r at col (lane&15) ----
  const int se = n0 + wv * 16 + (lane & 15);
  const int be = se / PLANE;
  const int spe = se % PLANE;
  float* cb = j.c_base + (size_t)be * (CHID * PLANE) + spe;
  float* hb = j.h_out + (size_t)be * j.ho_bs + spe;
  float* hfb = j.hf ? (j.hf + (size_t)be * (CHID * PLANE) + spe) : nullptr;

#pragma unroll
  for (int m = 0; m < 6; ++m) {
#pragma unroll
    for (int r = 0; r < 4; ++r) {
      const int ch = m * 16 + rbase + r;
      const float gi = acc[m][r];
      const float gf = acc[m + 6][r];
      const float go = acc[m + 12][r];
      const float gg = acc[m + 18][r];
      const float si = 1.f / (1.f + __expf(-gi));
      const float sf = 1.f / (1.f + __expf(-gf));
      const float so = 1.f / (1.f + __expf(-go));
      const float e2g = __expf(2.f * gg);
      const float tg = 1.f - 2.f / (e2g + 1.f);     // tanh(gg)
      const float cold = cb[(size_t)ch * PLANE];
      const float cn = sf * cold + si * tg;
      const float e2c = __expf(2.f * cn);
      const float tc = 1.f - 2.f / (e2c + 1.f);     // tanh(cn)
      const float hn = so * tc;
      cb[(size_t)ch * PLANE] = cn;
      hb[(size_t)ch * PLANE] = hn;
      if (hfb) hfb[(size_t)ch * PLANE] = hn;
    }
  }
}

extern "C" void kernel_launch(void* const* d_in, const int* in_sizes, int n_in,
                              void* d_out, int out_size, void* d_ws, size_t ws_size,
                              hipStream_t stream) {
  const float* inp  = (const float*)d_in[0];   // [8,12,96,48,48]
  const float* h0   = (const float*)d_in[1];   // [2,8,96,48,48]
  const float* c0   = (const float*)d_in[2];   // [2,8,96,48,48]
  const float* W    = (const float*)d_in[3];   // [2,384,192,3,3]
  const float* bias = (const float*)d_in[4];   // [2,384]

  float* AH = (float*)d_out;                               // [2,8,12,96,48,48]
  const size_t BT = (size_t)CHID * PLANE;                  // 221184 (one [96,48,48] block)
  float* HF = AH + (size_t)2 * NB * NT * BT;               // [2,8,96,48,48]
  float* CF = HF + (size_t)2 * NB * BT;                    // [2,8,96,48,48] (running c state)

  unsigned short* Wb = (unsigned short*)d_ws;              // [2][384][1728] bf16

  // 1) repack weights to bf16
  {
    int total = 2 * OC * KTOT;
    convlstm_wconv<<<(total + 255) / 256, 256, 0, stream>>>(W, Wb, total);
  }
  // 2) init running c state from c0
  hipMemcpyAsync(CF, c0, (size_t)2 * NB * BT * sizeof(float), hipMemcpyDeviceToDevice, stream);

  // 3) pipelined steps: launch k runs layer0(t=k) and layer1(t=k-1) concurrently
  auto mkjob = [&](int l, int t) -> Job {
    Job j;
    if (l == 0) { j.x_base = inp + (size_t)t * BT; j.x_bs = (long long)NT * BT; }
    else        { j.x_base = AH + (size_t)t * BT;  j.x_bs = (long long)NT * BT; }  // AH[0,b,t]
    if (t == 0) { j.h_base = h0 + (size_t)l * NB * BT; j.h_bs = (long long)BT; }
    else        { j.h_base = AH + (size_t)l * NB * NT * BT + (size_t)(t - 1) * BT;
                  j.h_bs = (long long)NT * BT; }
    j.w = Wb + (size_t)l * OC * KTOT;
    j.bias = bias + l * OC;
    j.c_base = CF + (size_t)l * NB * BT;
    j.h_out = AH + (size_t)l * NB * NT * BT + (size_t)t * BT;
    j.ho_bs = (long long)NT * BT;
    j.hf = (t == NT - 1) ? (HF + (size_t)l * NB * BT) : nullptr;
    return j;
  };

  for (int k = 0; k <= NT; ++k) {
    const bool hasA = (k <= NT - 1);   // layer0, t=k
    const bool hasB = (k >= 1);        // layer1, t=k-1
    Job ja, jb;
    int njobs = 0;
    if (hasA) { ja = mkjob(0, k); njobs = 1; }
    if (hasB) {
      Job x = mkjob(1, k - 1);
      if (njobs) jb = x; else ja = x;
      njobs++;
    }
    if (njobs == 1) jb = ja;
    convlstm_step<<<njobs * NBLK_JOB, 256, 0, stream>>>(ja, jb);
  }
}

// Round 2
// 1282.222 us; speedup vs baseline: 1.2561x; 1.2561x over previous
//
#include <hip/hip_runtime.h>
#include <hip/hip_bf16.h>
#include <stdint.h>

#define HWDIM 48
#define PLANE 2304            // 48*48
#define NB 8
#define NT 12
#define CHID 96
#define CIN 192               // C + HID
#define OC 384                // 4*HID
#define KTOT 1728             // CIN*9
#define BN 64                 // spatial cols per block
#define NBLK_JOB 288          // 18432 / 64
#define NCHUNK 54             // 1728 / 32

typedef __attribute__((ext_vector_type(8))) short short8;
typedef __attribute__((ext_vector_type(4))) float f32x4;

__device__ __forceinline__ unsigned short f2bf(float f) {
  union { float f; uint32_t u; } x; x.f = f;
  uint32_t u = x.u;
  return (unsigned short)((u + 0x7FFFu + ((u >> 16) & 1u)) >> 16);  // RNE
}

struct Job {
  const float* x_base; long long x_bs;   // x input: base + b*x_bs + ic*PLANE + y*48+x
  const float* h_base; long long h_bs;   // h_prev input
  const short8* w;                       // bf16 weights, fragment order [54][24][64 lanes][8]
  const float* bias;                     // [384]
  float* c_base;                         // c state, b-stride 96*PLANE
  float* h_out; long long ho_bs;         // h output (all_hidden slot)
  float* hf;                             // final-h slot or nullptr, b-stride 96*PLANE
};

// Weight repack: W[l][oc][ic][3][3] f32 -> fragment-direct bf16 layout per layer:
//   Wb[c][rm][lane][jj] = w_rowmajor[oc = rm*16 + (lane&15)][k = c*32 + (lane>>4)*8 + jj]
//   with k = (kh*3+kw)*192 + ic.  One coalesced b128 per MFMA A-fragment.
__global__ void convlstm_wconv(const float* __restrict__ W, unsigned short* __restrict__ Wb, int total) {
  int idx = blockIdx.x * 256 + threadIdx.x;
  if (idx >= total) return;
  const int PER_L = NCHUNK * 24 * 64 * 8;      // 663552
  int layer = idx / PER_L;
  int r = idx - layer * PER_L;
  int jj = r & 7;
  int l = (r >> 3) & 63;
  int fr = r >> 9;                  // c*24 + rm
  int rm = fr % 24;
  int c = fr / 24;
  int oc = rm * 16 + (l & 15);
  int k = c * 32 + ((l >> 4) << 3) + jj;
  int tap = k / CIN;
  int ic = k - tap * CIN;
  float v = W[(((size_t)layer * OC + oc) * CIN + ic) * 9 + tap];
  Wb[idx] = f2bf(v);
}

__global__ __launch_bounds__(256, 2) void convlstm_step(Job j0, Job j1) {
  __shared__ __align__(16) short8 bufB[2][256];   // [buf][kg*64 + col] : 8 KB
  __shared__ float GL[4 * 96 * 17];               // epilogue gate exchange: 25.5 KB

  const int tid = threadIdx.x;
  const Job j = (blockIdx.x < NBLK_JOB) ? j0 : j1;
  const int n0 = (blockIdx.x % NBLK_JOB) * BN;

  const int lane = tid & 63;
  const int g = tid >> 6;               // wave id == gate id (0:i 1:f 2:o 3:g)

  // ---- B staging role: thread owns (col = tid&63, kg = tid>>6) ----
  const int col = tid & 63;
  const int kg = tid >> 6;
  const int s = n0 + col;
  const int bb = s / PLANE;             // uniform per block (2304 % 64 == 0)
  const int sp = s % PLANE;
  const int y = sp / HWDIM;
  const int x = sp % HWDIM;
  const float* xpt = j.x_base + (size_t)bb * j.x_bs + (size_t)kg * 8 * PLANE;
  const float* hpt = j.h_base + (size_t)bb * j.h_bs + (size_t)kg * 8 * PLANE;

  // stage chunk c into bv[8] (im2col gather + zero pad)
  auto stage = [&](int c, float* bv) {
    const int wdx = c / 6;
    const int icc = c - wdx * 6;        // 0-2: x source, 3-5: h source
    const int kh = wdx / 3, kw = wdx - kh * 3;
    const int yy = y + kh - 1, xx = x + kw - 1;
    const bool valid = ((unsigned)yy < HWDIM) && ((unsigned)xx < HWDIM);
    const float* src = (icc < 3) ? (xpt + (size_t)icc * 32 * PLANE)
                                 : (hpt + (size_t)(icc - 3) * 32 * PLANE);
    const int off = yy * HWDIM + xx;
#pragma unroll
    for (int i = 0; i < 8; ++i) bv[i] = 0.f;
    if (valid) {
#pragma unroll
      for (int i = 0; i < 8; ++i) bv[i] = src[(size_t)(off) + (size_t)i * PLANE];
    }
  };

  // ---- accumulators: wave g covers rows [g*96, g*96+96) x cols [n0, n0+64) ----
  f32x4 acc[6][4];
#pragma unroll
  for (int rm = 0; rm < 6; ++rm) {
    f32x4 bi = *(const f32x4*)(j.bias + g * 96 + rm * 16 + ((lane >> 4) << 2));
#pragma unroll
    for (int cn = 0; cn < 4; ++cn) acc[rm][cn] = bi;
  }

  // ---- prologue: stage chunk 0, load A frags chunk 0 ----
  float bv[8];
  stage(0, bv);
  short8 a_cur[6];
#pragma unroll
  for (int rm = 0; rm < 6; ++rm)
    a_cur[rm] = j.w[(size_t)(0 * 24 + g * 6 + rm) * 64 + lane];
  {
    short8 pb;
#pragma unroll
    for (int i = 0; i < 8; ++i) pb[i] = (short)f2bf(bv[i]);
    bufB[0][tid] = pb;
  }
  __syncthreads();

  // ---- main loop: 1 barrier per chunk; A reg-prefetch 1 ahead; B LDS double-buffered ----
#pragma unroll 2
  for (int c = 0; c < NCHUNK; ++c) {
    const int cb = c & 1;
    float nv[8];
    short8 a_nxt[6];
    if (c + 1 < NCHUNK) {
      stage(c + 1, nv);
#pragma unroll
      for (int rm = 0; rm < 6; ++rm)
        a_nxt[rm] = j.w[(size_t)((c + 1) * 24 + g * 6 + rm) * 64 + lane];
    }
    // B fragments (same data for all 4 waves)
    short8 bf[4];
#pragma unroll
    for (int cn = 0; cn < 4; ++cn)
      bf[cn] = bufB[cb][((lane >> 4) << 6) + cn * 16 + (lane & 15)];
#pragma unroll
    for (int cn = 0; cn < 4; ++cn)
#pragma unroll
      for (int rm = 0; rm < 6; ++rm)
        acc[rm][cn] = __builtin_amdgcn_mfma_f32_16x16x32_bf16(a_cur[rm], bf[cn], acc[rm][cn], 0, 0, 0);
    if (c + 1 < NCHUNK) {
      short8 pb;
#pragma unroll
      for (int i = 0; i < 8; ++i) pb[i] = (short)f2bf(nv[i]);
      bufB[cb ^ 1][tid] = pb;
    }
    __syncthreads();
#pragma unroll
    for (int rm = 0; rm < 6; ++rm) a_cur[rm] = a_nxt[rm];
  }

  // ---- epilogue: gate exchange via LDS, fused LSTM pointwise ----
#pragma unroll
  for (int cc = 0; cc < 4; ++cc) {
    if (cc) __syncthreads();
#pragma unroll
    for (int rm = 0; rm < 6; ++rm)
#pragma unroll
      for (int r = 0; r < 4; ++r)
        GL[(g * 96 + rm * 16 + ((lane >> 4) << 2) + r) * 17 + (lane & 15)] = acc[rm][cc][r];
    __syncthreads();

    const int colL = tid & 15;
    const int chb = (tid >> 4) * 6;
    const int se = n0 + cc * 16 + colL;
    const int be = se / PLANE;
    const int spe = se % PLANE;
    float* cb_ = j.c_base + (size_t)be * (CHID * PLANE) + spe;
    float* hb_ = j.h_out + (size_t)be * j.ho_bs + spe;
    float* hf_ = j.hf ? (j.hf + (size_t)be * (CHID * PLANE) + spe) : nullptr;
#pragma unroll
    for (int q = 0; q < 6; ++q) {
      const int ch = chb + q;
      const float gi = GL[(0 * 96 + ch) * 17 + colL];
      const float gf = GL[(1 * 96 + ch) * 17 + colL];
      const float go = GL[(2 * 96 + ch) * 17 + colL];
      const float gg = GL[(3 * 96 + ch) * 17 + colL];
      const float si = 1.f / (1.f + __expf(-gi));
      const float sf = 1.f / (1.f + __expf(-gf));
      const float so = 1.f / (1.f + __expf(-go));
      const float e2g = __expf(2.f * gg);
      const float tg = 1.f - 2.f / (e2g + 1.f);     // tanh(gg)
      const float cold = cb_[(size_t)ch * PLANE];
      const float cn2 = sf * cold + si * tg;
      const float e2c = __expf(2.f * cn2);
      const float tc = 1.f - 2.f / (e2c + 1.f);     // tanh(cn)
      const float hn = so * tc;
      cb_[(size_t)ch * PLANE] = cn2;
      hb_[(size_t)ch * PLANE] = hn;
      if (hf_) hf_[(size_t)ch * PLANE] = hn;
    }
  }
}

extern "C" void kernel_launch(void* const* d_in, const int* in_sizes, int n_in,
                              void* d_out, int out_size, void* d_ws, size_t ws_size,
                              hipStream_t stream) {
  const float* inp  = (const float*)d_in[0];   // [8,12,96,48,48]
  const float* h0   = (const float*)d_in[1];   // [2,8,96,48,48]
  const float* c0   = (const float*)d_in[2];   // [2,8,96,48,48]
  const float* W    = (const float*)d_in[3];   // [2,384,192,3,3]
  const float* bias = (const float*)d_in[4];   // [2,384]

  float* AH = (float*)d_out;                               // [2,8,12,96,48,48]
  const size_t BT = (size_t)CHID * PLANE;                  // 221184
  float* HF = AH + (size_t)2 * NB * NT * BT;               // [2,8,96,48,48]
  float* CF = HF + (size_t)2 * NB * BT;                    // [2,8,96,48,48] running c

  unsigned short* Wb = (unsigned short*)d_ws;              // [2][54][24][64][8] bf16

  // 1) repack weights to bf16 fragment order
  {
    int total = 2 * NCHUNK * 24 * 64 * 8;
    convlstm_wconv<<<(total + 255) / 256, 256, 0, stream>>>(W, Wb, total);
  }
  // 2) init running c state from c0
  hipMemcpyAsync(CF, c0, (size_t)2 * NB * BT * sizeof(float), hipMemcpyDeviceToDevice, stream);

  const size_t PER_L = (size_t)NCHUNK * 24 * 64;           // short8 units per layer

  // 3) pipelined steps: launch k runs layer0(t=k) and layer1(t=k-1) concurrently
  auto mkjob = [&](int l, int t) -> Job {
    Job j;
    if (l == 0) { j.x_base = inp + (size_t)t * BT; j.x_bs = (long long)NT * BT; }
    else        { j.x_base = AH + (size_t)t * BT;  j.x_bs = (long long)NT * BT; }  // AH[0,b,t]
    if (t == 0) { j.h_base = h0 + (size_t)l * NB * BT; j.h_bs = (long long)BT; }
    else        { j.h_base = AH + (size_t)l * NB * NT * BT + (size_t)(t - 1) * BT;
                  j.h_bs = (long long)NT * BT; }
    j.w = (const short8*)Wb + (size_t)l * PER_L;
    j.bias = bias + l * OC;
    j.c_base = CF + (size_t)l * NB * BT;
    j.h_out = AH + (size_t)l * NB * NT * BT + (size_t)t * BT;
    j.ho_bs = (long long)NT * BT;
    j.hf = (t == NT - 1) ? (HF + (size_t)l * NB * BT) : nullptr;
    return j;
  };

  for (int k = 0; k <= NT; ++k) {
    const bool hasA = (k <= NT - 1);   // layer0, t=k
    const bool hasB = (k >= 1);        // layer1, t=k-1
    Job ja, jb;
    int njobs = 0;
    if (hasA) { ja = mkjob(0, k); njobs = 1; }
    if (hasB) {
      Job x = mkjob(1, k - 1);
      if (njobs) jb = x; else ja = x;
      njobs++;
    }
    if (njobs == 1) jb = ja;
    convlstm_step<<<njobs * NBLK_JOB, 256, 0, stream>>>(ja, jb);
  }
}

// Round 3
// 879.969 us; speedup vs baseline: 1.8303x; 1.4571x over previous
//
#include <hip/hip_runtime.h>
#include <hip/hip_bf16.h>
#include <stdint.h>

#define HWDIM 48
#define PLANE 2304            // 48*48
#define NB 8
#define NT 12
#define CHID 96
#define OC 384                // 4*HID
#define KTOT 1728
#define BN 64                 // spatial cols per block
#define NBLK_JOB 288          // 18432 / 64
#define NCHUNK 54             // 1728 / 32
#define PPLANE 2500           // 50*50 (48x48 interior + zero halo)
#define PGRP 3                // 32-ch groups per 96-ch image
#define IMG_E ((size_t)PGRP * PPLANE * 32)     // packed elems per image = 240000
#define SLOT_E ((size_t)NB * IMG_E)            // packed elems per slot (8 imgs)
#define BT ((size_t)CHID * PLANE)              // 221184

typedef __attribute__((ext_vector_type(8))) short short8;
typedef __attribute__((ext_vector_type(4))) float f32x4;
typedef __attribute__((ext_vector_type(4))) unsigned int u32x4;

__device__ __forceinline__ unsigned short f2bf(float f) {
  union { float f; uint32_t u; } x; x.f = f;
  uint32_t u = x.u;
  return (unsigned short)((u + 0x7FFFu + ((u >> 16) & 1u)) >> 16);  // RNE
}

// ---------------- weight repack (fragment-direct, same as r2) ----------------
__global__ void convlstm_wconv(const float* __restrict__ W, unsigned short* __restrict__ Wb, int total) {
  int idx = blockIdx.x * 256 + threadIdx.x;
  if (idx >= total) return;
  const int PER_L = NCHUNK * 24 * 64 * 8;      // 663552
  int layer = idx / PER_L;
  int r = idx - layer * PER_L;
  int jj = r & 7;
  int l = (r >> 3) & 63;
  int fr = r >> 9;                  // c*24 + rm
  int rm = fr % 24;
  int c = fr / 24;
  int oc = rm * 16 + (l & 15);
  int k = c * 32 + ((l >> 4) << 3) + jj;
  int tap = k / 192;
  int ic = k - tap * 192;
  float v = W[(((size_t)layer * OC + oc) * 192 + ic) * 9 + tap];
  Wb[idx] = f2bf(v);
}

// ---------------- activation packing: f32 [img][96][2304] -> bf16 [slot][3][50][50][32] interior ----------------
__global__ void pack_interior(const float* __restrict__ src, unsigned short* __restrict__ dst,
                              int mode, int t_base, int slot_mask) {
  __shared__ float T[32][65];
  int bid = blockIdx.x;
  int tile = bid % 36;
  int grp  = (bid / 36) % 3;
  int imgi = bid / 108;
  int slot; size_t srcoff;
  if (mode == 0) {                  // x: imgi = (t - t_base)*8 + b
    int b = imgi & 7; int t = t_base + (imgi >> 3);
    srcoff = ((size_t)b * NT + t) * BT;
    slot = (t & slot_mask) * NB + b;
  } else {                          // h0: imgi = l*8 + b -> ph slot (l*2+1), image b
    int b = imgi & 7; int l = imgi >> 3;
    srcoff = (size_t)imgi * BT;
    slot = (l * 2 + 1) * NB + b;
  }
  const float* s = src + srcoff + (size_t)grp * 32 * PLANE + tile * 64;
  const int tid = threadIdx.x;
#pragma unroll
  for (int r = 0; r < 8; ++r) {
    int ch = r * 4 + (tid >> 6);
    T[ch][tid & 63] = s[(size_t)ch * PLANE + (tid & 63)];
  }
  __syncthreads();
  int p = tid >> 2, sq = tid & 3;
  int pos = tile * 64 + p;
  int py = pos / 48 + 1, px = pos % 48 + 1;
  unsigned short v[8];
#pragma unroll
  for (int i = 0; i < 8; ++i) v[i] = f2bf(T[sq * 8 + i][p]);
  *(short8*)(dst + ((size_t)slot * PGRP + grp) * (PPLANE * 32) + (py * 50 + px) * 32 + sq * 8) = *(short8*)v;
}

// zero the halo border of packed planes (196 granules per [50][50][32] plane)
__global__ void border_zero(unsigned short* dst, int nplanes) {
  int idx = blockIdx.x * 256 + threadIdx.x;
  if (idx >= nplanes * 784) return;
  int plane = idx / 784;
  int r = idx - plane * 784;
  int g = r >> 2, sq = r & 3;
  int py, px;
  if (g < 50)       { py = 0;       px = g; }
  else if (g < 100) { py = 49;      px = g - 50; }
  else if (g < 148) { py = g - 99;  px = 0; }
  else              { py = g - 147; px = 49; }
  u32x4 z = {0, 0, 0, 0};
  *(u32x4*)(dst + (size_t)plane * (PPLANE * 32) + (py * 50 + px) * 32 + sq * 8) = z;
}

// ---------------- fused conv + LSTM step ----------------
struct Job {
  const unsigned short* xp;   // packed x source [8][3][2500][32] bf16
  const unsigned short* hp;   // packed h_prev source
  unsigned short* hw;         // packed h dest (parity t)
  const short8* w;            // bf16 weights fragment order [54][24][64][8]
  const float* bias;          // [384]
  float* c_base;              // c state, b-stride 96*PLANE
  float* h_out; long long ho_bs;
  float* hf;                  // final-h slot or nullptr
};

__global__ __launch_bounds__(256, 2) void convlstm_step(Job j0, Job j1) {
  __shared__ __align__(16) char smem[26112 + 12288];
  short8* bufB = (short8*)smem;                          // [2][4 q][64 col] granules = 8KB (aliases GL)
  float* GL = (float*)smem;                              // [384][17] f32 = 26112B (epilogue)
  unsigned short* HP = (unsigned short*)(smem + 26112);  // [64 pos][96 ch] bf16 = 12KB (epilogue)

  const int tid = threadIdx.x;
  const Job j = (blockIdx.x < NBLK_JOB) ? j0 : j1;
  const int n0 = (blockIdx.x % NBLK_JOB) * BN;
  const int lane = tid & 63;
  const int g = tid >> 6;               // wave id == gate id (0:i 1:f 2:o 3:g) == staged k-quarter

  const int bb = n0 / PLANE;            // uniform per block
  const int spb = n0 - bb * PLANE;
  const int y = (spb + lane) / HWDIM;
  const int x = (spb + lane) % HWDIM;
  const size_t vcen = (size_t)bb * IMG_E + (size_t)((y + 1) * 50 + (x + 1)) * 32 + g * 8;
  const unsigned short* xcen = j.xp + vcen;
  const unsigned short* hcen = j.hp + vcen;

  // chunk c -> per-lane source granule address (tap/group offsets are wave-uniform)
  auto src_of = [&](int c) -> const unsigned short* {
    int tap = c / 6, grp = c - tap * 6;
    int kh = tap / 3, kw = tap - kh * 3;
    int doff = ((kh - 1) * 50 + (kw - 1)) * 32;
    const unsigned short* base = (grp < 3) ? (xcen + grp * (PPLANE * 32))
                                           : (hcen + (grp - 3) * (PPLANE * 32));
    return base + doff;
  };

  // accumulators: wave g covers gate-g rows [g*96, g*96+96) x cols [n0, n0+64)
  f32x4 acc[6][4];
#pragma unroll
  for (int rm = 0; rm < 6; ++rm) {
    f32x4 bi = *(const f32x4*)(j.bias + g * 96 + rm * 16 + ((lane >> 4) << 2));
#pragma unroll
    for (int cn = 0; cn < 4; ++cn) acc[rm][cn] = bi;
  }

  const short8* aw = j.w + (size_t)g * 6 * 64 + lane;    // + c*1536 + rm*64

  // prologue: stage chunk 0, A frags chunk 0
  bufB[0 * 256 + g * 64 + lane] = *(const short8*)src_of(0);
  short8 a_cur[6];
#pragma unroll
  for (int rm = 0; rm < 6; ++rm) a_cur[rm] = aw[rm * 64];
  __syncthreads();

  // main loop: 1 barrier/chunk, B double-buffered in LDS, A reg-prefetched 1 ahead
  for (int c = 0; c < NCHUNK; ++c) {
    short8 bnew;
    short8 a_nxt[6];
    if (c + 1 < NCHUNK) {
      bnew = *(const short8*)src_of(c + 1);
#pragma unroll
      for (int rm = 0; rm < 6; ++rm) a_nxt[rm] = aw[(size_t)(c + 1) * 1536 + rm * 64];
    }
    short8 bf[4];
#pragma unroll
    for (int cn = 0; cn < 4; ++cn)
      bf[cn] = bufB[(c & 1) * 256 + ((lane >> 4) << 6) + cn * 16 + (lane & 15)];
#pragma unroll
    for (int cn = 0; cn < 4; ++cn)
#pragma unroll
      for (int rm = 0; rm < 6; ++rm)
        acc[rm][cn] = __builtin_amdgcn_mfma_f32_16x16x32_bf16(a_cur[rm], bf[cn], acc[rm][cn], 0, 0, 0);
    if (c + 1 < NCHUNK)
      bufB[((c + 1) & 1) * 256 + g * 64 + lane] = bnew;
    __syncthreads();
#pragma unroll
    for (int rm = 0; rm < 6; ++rm) a_cur[rm] = a_nxt[rm];
  }

  // epilogue: gate exchange via GL, fused LSTM pointwise, + packed-h staging in HP
#pragma unroll
  for (int cc = 0; cc < 4; ++cc) {
    if (cc) __syncthreads();
#pragma unroll
    for (int rm = 0; rm < 6; ++rm)
#pragma unroll
      for (int r = 0; r < 4; ++r)
        GL[(g * 96 + rm * 16 + ((lane >> 4) << 2) + r) * 17 + (lane & 15)] = acc[rm][cc][r];
    __syncthreads();

    const int colL = tid & 15;
    const int chb = (tid >> 4) * 6;
    const int spe = spb + cc * 16 + colL;
    float* cb_ = j.c_base + (size_t)bb * (CHID * PLANE) + spe;
    float* hb_ = j.h_out + (size_t)bb * j.ho_bs + spe;
    float* hf_ = j.hf ? (j.hf + (size_t)bb * (CHID * PLANE) + spe) : nullptr;
#pragma unroll
    for (int q = 0; q < 6; ++q) {
      const int ch = chb + q;
      const float gi = GL[(0 * 96 + ch) * 17 + colL];
      const float gf = GL[(1 * 96 + ch) * 17 + colL];
      const float go = GL[(2 * 96 + ch) * 17 + colL];
      const float gg = GL[(3 * 96 + ch) * 17 + colL];
      const float si = 1.f / (1.f + __expf(-gi));
      const float sf = 1.f / (1.f + __expf(-gf));
      const float so = 1.f / (1.f + __expf(-go));
      const float e2g = __expf(2.f * gg);
      const float tg = 1.f - 2.f / (e2g + 1.f);     // tanh(gg)
      const float cold = cb_[(size_t)ch * PLANE];
      const float cn2 = sf * cold + si * tg;
      const float e2c = __expf(2.f * cn2);
      const float tc = 1.f - 2.f / (e2c + 1.f);     // tanh(cn)
      const float hn = so * tc;
      cb_[(size_t)ch * PLANE] = cn2;
      hb_[(size_t)ch * PLANE] = hn;
      if (hf_) hf_[(size_t)ch * PLANE] = hn;
      HP[(cc * 16 + colL) * 96 + ch] = f2bf(hn);
    }
  }
  __syncthreads();

  // coalesced packed-h store: thread -> (pos p, 16B quarter sq), 3 channel groups
  {
    const int p = tid >> 2, sq = tid & 3;
    const int pos = spb + p;
    const int py = pos / 48 + 1, px = pos % 48 + 1;
#pragma unroll
    for (int grp = 0; grp < 3; ++grp) {
      short8 v = *(short8*)&HP[p * 96 + grp * 32 + sq * 8];
      *(short8*)(j.hw + (size_t)bb * IMG_E + (size_t)grp * (PPLANE * 32) + (py * 50 + px) * 32 + sq * 8) = v;
    }
  }
}

extern "C" void kernel_launch(void* const* d_in, const int* in_sizes, int n_in,
                              void* d_out, int out_size, void* d_ws, size_t ws_size,
                              hipStream_t stream) {
  const float* inp  = (const float*)d_in[0];   // [8,12,96,48,48]
  const float* h0   = (const float*)d_in[1];   // [2,8,96,48,48]
  const float* c0   = (const float*)d_in[2];   // [2,8,96,48,48]
  const float* W    = (const float*)d_in[3];   // [2,384,192,3,3]
  const float* bias = (const float*)d_in[4];   // [2,384]

  float* AH = (float*)d_out;                   // [2,8,12,96,48,48]
  float* HF = AH + (size_t)2 * NB * NT * BT;   // [2,8,96,48,48]
  float* CF = HF + (size_t)2 * NB * BT;        // [2,8,96,48,48] running c

  // workspace layout: [Wb | ph (4 slots) | px (12 or 2 slots)]
  const size_t WB_BYTES = (size_t)2 * NCHUNK * 24 * 64 * 8 * 2;          // 2,654,208
  const size_t PH_BYTES = (size_t)4 * SLOT_E * 2;                        // 15,360,000
  const size_t PX_BIG   = (size_t)NT * SLOT_E * 2;                       // 46,080,000
  const bool big = ws_size >= WB_BYTES + PH_BYTES + PX_BIG;
  unsigned short* Wb = (unsigned short*)d_ws;
  unsigned short* ph = (unsigned short*)((char*)d_ws + WB_BYTES);
  unsigned short* px = (unsigned short*)((char*)d_ws + WB_BYTES + PH_BYTES);

  // 1) repack weights
  {
    int total = 2 * NCHUNK * 24 * 64 * 8;
    convlstm_wconv<<<(total + 255) / 256, 256, 0, stream>>>(W, Wb, total);
  }
  // 2) zero halo borders (ph: 4 slots * 8 imgs * 3 grp planes; px: 12|2 slots)
  {
    int np_ph = 4 * NB * 3;
    border_zero<<<(np_ph * 784 + 255) / 256, 256, 0, stream>>>(ph, np_ph);
    int np_px = (big ? NT : 2) * NB * 3;
    border_zero<<<(np_px * 784 + 255) / 256, 256, 0, stream>>>(px, np_px);
  }
  // 3) pack x (all t if big, else t=0,1) and h0
  {
    int n_img = big ? (NT * NB) : (2 * NB);
    pack_interior<<<n_img * 108, 256, 0, stream>>>(inp, px, 0, 0, big ? 15 : 1);
    pack_interior<<<2 * NB * 108, 256, 0, stream>>>(h0, ph, 1, 0, 0);
  }
  // 4) running c state
  hipMemcpyAsync(CF, c0, (size_t)2 * NB * BT * sizeof(float), hipMemcpyDeviceToDevice, stream);

  const size_t PER_L = (size_t)NCHUNK * 24 * 64;   // short8 units per layer

  auto mkjob = [&](int l, int t) -> Job {
    Job j;
    if (l == 0) j.xp = px + (size_t)(big ? t : (t & 1)) * SLOT_E;
    else        j.xp = ph + (size_t)(0 * 2 + (t & 1)) * SLOT_E;          // layer0's packed h at t
    j.hp = ph + (size_t)(l * 2 + ((t + 1) & 1)) * SLOT_E;                // parity of t-1
    j.hw = ph + (size_t)(l * 2 + (t & 1)) * SLOT_E;
    j.w = (const short8*)Wb + (size_t)l * PER_L;
    j.bias = bias + l * OC;
    j.c_base = CF + (size_t)l * NB * BT;
    j.h_out = AH + (size_t)l * NB * NT * BT + (size_t)t * BT;
    j.ho_bs = (long long)NT * BT;
    j.hf = (t == NT - 1) ? (HF + (size_t)l * NB * BT) : nullptr;
    return j;
  };

  for (int k = 0; k <= NT; ++k) {
    const bool hasA = (k <= NT - 1);   // layer0, t=k
    const bool hasB = (k >= 1);        // layer1, t=k-1
    Job ja, jb;
    int njobs = 0;
    if (hasA) { ja = mkjob(0, k); njobs = 1; }
    if (hasB) {
      Job xj = mkjob(1, k - 1);
      if (njobs) jb = xj; else ja = xj;
      njobs++;
    }
    if (njobs == 1) jb = ja;
    convlstm_step<<<njobs * NBLK_JOB, 256, 0, stream>>>(ja, jb);
    if (!big && k + 2 <= NT - 1)       // pack x for t=k+2 into slot (k+2)&1 (freed by step k)
      pack_interior<<<NB * 108, 256, 0, stream>>>(inp, px, 0, k + 2, 1);
  }
}